// Round 1
// baseline (878.046 us; speedup 1.0000x reference)
//
#include <hip/hip_runtime.h>
#include <math.h>

#define N_NODES 100000
#define B_GRAPH 1024
#define NPART 391   // ceil(N/256)

static inline size_t alignup(size_t x){ return (x + 255) & ~(size_t)255; }

// ---------------- CSR build ----------------
__global__ __launch_bounds__(256) void k_deg(const int* __restrict__ dst, int* __restrict__ deg, int E){
  int e = blockIdx.x*256 + threadIdx.x;
  if (e < E) atomicAdd(&deg[dst[e]], 1);
}

__global__ __launch_bounds__(256) void k_part(const int* __restrict__ deg, int* __restrict__ part, int Nn){
  __shared__ int red[256];
  int t = threadIdx.x; int i = blockIdx.x*256 + t;
  red[t] = (i < Nn) ? deg[i] : 0;
  __syncthreads();
  for (int s = 128; s > 0; s >>= 1){ if (t < s) red[t] += red[t+s]; __syncthreads(); }
  if (t == 0) part[blockIdx.x] = red[0];
}

__global__ __launch_bounds__(512) void k_scanpart(int* __restrict__ part, int np){
  __shared__ int sc[512];
  int t = threadIdx.x;
  int v = (t < np) ? part[t] : 0;
  sc[t] = v; __syncthreads();
  for (int off = 1; off < 512; off <<= 1){
    int u = (t >= off) ? sc[t-off] : 0;
    __syncthreads();
    sc[t] += u;
    __syncthreads();
  }
  if (t < np) part[t] = sc[t] - v;  // exclusive prefix of block sums
}

__global__ __launch_bounds__(256) void k_rowptr(const int* __restrict__ deg, const int* __restrict__ part,
                                                int* __restrict__ rp, int* __restrict__ cur, int Nn){
  __shared__ int sc[256];
  int t = threadIdx.x; int i = blockIdx.x*256 + t;
  int v = (i < Nn) ? deg[i] : 0;
  sc[t] = v; __syncthreads();
  for (int off = 1; off < 256; off <<= 1){
    int u = (t >= off) ? sc[t-off] : 0;
    __syncthreads();
    sc[t] += u;
    __syncthreads();
  }
  int excl = sc[t] - v + part[blockIdx.x];
  if (i < Nn){
    rp[i] = excl; cur[i] = excl;
    if (i == Nn-1) rp[Nn] = excl + v;
  }
}

__global__ __launch_bounds__(256) void k_fill(const int* __restrict__ src, const int* __restrict__ dst,
                                              int* __restrict__ cur, int* __restrict__ col, int E){
  int e = blockIdx.x*256 + threadIdx.x;
  if (e < E){
    int slot = atomicAdd(&cur[dst[e]], 1);
    col[slot] = src[e];
  }
}

// ---------------- GCN layer 1: t1 = feat @ Wg1 ----------------
__global__ __launch_bounds__(256) void k_gemm1(const float* __restrict__ feat, const float* __restrict__ W,
                                               float* __restrict__ t1, int Nn){
  int row = blockIdx.x*256 + threadIdx.x;
  if (row >= Nn) return;
  const float4* f4 = reinterpret_cast<const float4*>(feat + (size_t)row*128);
  float acc[100];
  #pragma unroll
  for (int j = 0; j < 100; j++) acc[j] = 0.f;
  for (int kc = 0; kc < 32; kc++){
    float4 f = f4[kc];
    const float* w0 = W + kc*400;   // (4*kc)*100
    #pragma unroll
    for (int j = 0; j < 100; j++){
      float a = acc[j];
      a = fmaf(f.x, w0[j],       a);
      a = fmaf(f.y, w0[100 + j], a);
      a = fmaf(f.z, w0[200 + j], a);
      a = fmaf(f.w, w0[300 + j], a);
      acc[j] = a;
    }
  }
  float4* o4 = reinterpret_cast<float4*>(t1 + (size_t)row*100);
  #pragma unroll
  for (int j = 0; j < 25; j++){
    float4 v; v.x = acc[4*j]; v.y = acc[4*j+1]; v.z = acc[4*j+2]; v.w = acc[4*j+3];
    o4[j] = v;
  }
}

// ---------------- aggregation, D=100: h1 = relu(mean_in(t1) + bg1) ----------------
__global__ __launch_bounds__(256) void k_agg1(const float* __restrict__ t1, const int* __restrict__ rp,
                                              const int* __restrict__ col, const float* __restrict__ bias,
                                              float* __restrict__ h1, int Nn){
  int tid = threadIdx.x;
  int node = blockIdx.x*2 + (tid >> 7);
  int d = tid & 127;
  if (node >= Nn || d >= 100) return;
  int rs = rp[node], re = rp[node+1];
  float s = 0.f;
  for (int e = rs; e < re; e++){
    int c = col[e];
    s += t1[(size_t)c*100 + d];
  }
  float v = s / (float)(re - rs) + bias[d];
  h1[(size_t)node*100 + d] = v > 0.f ? v : 0.f;
}

// ---------------- GCN layer 2 GEMM: t2 = h1 @ Wg2 (100->20) ----------------
__global__ __launch_bounds__(256) void k_gemm2(const float* __restrict__ h1, const float* __restrict__ W,
                                               float* __restrict__ t2, int Nn){
  int row = blockIdx.x*256 + threadIdx.x;
  if (row >= Nn) return;
  const float4* f4 = reinterpret_cast<const float4*>(h1 + (size_t)row*100);
  float acc[20];
  #pragma unroll
  for (int j = 0; j < 20; j++) acc[j] = 0.f;
  for (int kc = 0; kc < 25; kc++){
    float4 f = f4[kc];
    const float* w0 = W + kc*80;    // (4*kc)*20
    #pragma unroll
    for (int j = 0; j < 20; j++){
      float a = acc[j];
      a = fmaf(f.x, w0[j],      a);
      a = fmaf(f.y, w0[20 + j], a);
      a = fmaf(f.z, w0[40 + j], a);
      a = fmaf(f.w, w0[60 + j], a);
      acc[j] = a;
    }
  }
  float4* o4 = reinterpret_cast<float4*>(t2 + (size_t)row*20);
  #pragma unroll
  for (int j = 0; j < 5; j++){
    float4 v; v.x = acc[4*j]; v.y = acc[4*j+1]; v.z = acc[4*j+2]; v.w = acc[4*j+3];
    o4[j] = v;
  }
}

// ---------------- aggregation, D=20 ----------------
__global__ __launch_bounds__(256) void k_agg2(const float* __restrict__ t2, const int* __restrict__ rp,
                                              const int* __restrict__ col, const float* __restrict__ bias,
                                              float* __restrict__ h2, int Nn){
  int tid = threadIdx.x;
  int node = blockIdx.x*8 + (tid >> 5);
  int d = tid & 31;
  if (node >= Nn || d >= 20) return;
  int rs = rp[node], re = rp[node+1];
  float s = 0.f;
  for (int e = rs; e < re; e++){
    int c = col[e];
    s += t2[(size_t)c*20 + d];
  }
  float v = s / (float)(re - rs) + bias[d];
  h2[(size_t)node*20 + d] = v > 0.f ? v : 0.f;
}

// ---------------- per-graph mean: hg[g] = mean over nodes of h2 ----------------
__global__ __launch_bounds__(64) void k_gmean(const float* __restrict__ h2, float* __restrict__ hg){
  int g = blockIdx.x;
  int d = threadIdx.x;
  if (d >= 20) return;
  int s = (int)(((long long)g      * N_NODES + B_GRAPH - 1) / B_GRAPH);
  int e = (int)(((long long)(g+1)  * N_NODES + B_GRAPH - 1) / B_GRAPH);
  float acc = 0.f;
  for (int n = s; n < e; n++) acc += h2[(size_t)n*20 + d];
  hg[g*20 + d] = acc / (float)(e - s);
}

// ---------------- head: h_g = hg@Wpg+bpg ; h_d = desc2@Wp2+bp2 ----------------
__global__ __launch_bounds__(256) void k_head1(const float* __restrict__ hg, const float* __restrict__ Wpg,
                                               const float* __restrict__ bpg, const float* __restrict__ desc2,
                                               const float* __restrict__ Wp2, const float* __restrict__ bp2,
                                               float* __restrict__ hG, float* __restrict__ hD){
  int idx = blockIdx.x*256 + threadIdx.x;
  if (idx >= B_GRAPH*64) return;
  int r = idx >> 6, d = idx & 63;
  float a = bpg[d];
  for (int k = 0; k < 20; k++) a = fmaf(hg[r*20 + k], Wpg[k*64 + d], a);
  hG[r*64 + d] = a;
  float c = bp2[d];
  for (int k = 0; k < 200; k++) c = fmaf(desc2[r*200 + k], Wp2[k*64 + d], c);
  hD[r*64 + d] = c;
}

// ---------------- head: gate + fusion ----------------
__global__ __launch_bounds__(256) void k_head2(const float* __restrict__ hG, const float* __restrict__ hD,
                                               const float* __restrict__ W2, float* __restrict__ fus){
  int idx = blockIdx.x*256 + threadIdx.x;
  if (idx >= B_GRAPH*64) return;
  int r = idx >> 6, d = idx & 63;
  float x = 0.f;
  for (int k = 0; k < 64; k++) x = fmaf(hG[r*64 + k], W2[k*64 + d], x);
  float hd = hD[r*64 + d];
  float gv = 1.f / (1.f + expf(-x*hd));
  fus[r*128 + d]      = hG[r*64 + d];
  fus[r*128 + 64 + d] = gv*hd;
}

// ---------------- fused linear + BatchNorm(train stats) + relu ----------------
// one block per output column j; 256 threads x 4 rows = 1024 batch rows
__global__ __launch_bounds__(256) void k_bn(const float* __restrict__ X, const float* __restrict__ W,
                                            const float* __restrict__ bias, const float* __restrict__ gam,
                                            const float* __restrict__ bet, float* __restrict__ Y,
                                            int Kin, int Jout){
  int j = blockIdx.x;
  int t = threadIdx.x;
  float z[4];
  #pragma unroll
  for (int i = 0; i < 4; i++){
    int r = t + i*256;
    const float* xr = X + (size_t)r*Kin;
    float a = bias[j];
    for (int k = 0; k < Kin; k++) a = fmaf(xr[k], W[k*Jout + j], a);
    z[i] = a;
  }
  float s = z[0]+z[1]+z[2]+z[3];
  float q = z[0]*z[0]+z[1]*z[1]+z[2]*z[2]+z[3]*z[3];
  __shared__ float rs_[256], rq_[256];
  rs_[t] = s; rq_[t] = q; __syncthreads();
  for (int o = 128; o > 0; o >>= 1){
    if (t < o){ rs_[t] += rs_[t+o]; rq_[t] += rq_[t+o]; }
    __syncthreads();
  }
  float mu  = rs_[0] * (1.f/1024.f);
  float var = rq_[0] * (1.f/1024.f) - mu*mu;
  float inv = 1.f / sqrtf(var + 1e-5f);
  float gj = gam[j], bj = bet[j];
  #pragma unroll
  for (int i = 0; i < 4; i++){
    int r = t + i*256;
    float v = gj*(z[i]-mu)*inv + bj;
    Y[(size_t)r*Jout + j] = v > 0.f ? v : 0.f;
  }
}

// ---------------- final linear [B,32]@[32,1] ----------------
__global__ __launch_bounds__(256) void k_out(const float* __restrict__ y2, const float* __restrict__ Wf3,
                                             const float* __restrict__ bf3, float* __restrict__ out){
  int r = blockIdx.x*256 + threadIdx.x;
  if (r >= B_GRAPH) return;
  float a = bf3[0];
  #pragma unroll
  for (int k = 0; k < 32; k++) a = fmaf(y2[r*32 + k], Wf3[k], a);
  out[r] = a;
}

extern "C" void kernel_launch(void* const* d_in, const int* in_sizes, int n_in,
                              void* d_out, int out_size, void* d_ws, size_t ws_size,
                              hipStream_t stream){
  const float* feat  = (const float*)d_in[0];
  const int*   src   = (const int*)d_in[1];
  const int*   dst   = (const int*)d_in[2];
  const float* desc2 = (const float*)d_in[4];
  const float* Wg1   = (const float*)d_in[6];
  const float* bg1   = (const float*)d_in[7];
  const float* Wg2   = (const float*)d_in[8];
  const float* bg2   = (const float*)d_in[9];
  const float* Wpg   = (const float*)d_in[10];
  const float* bpg   = (const float*)d_in[11];
  const float* Wp2   = (const float*)d_in[12];
  const float* bp2   = (const float*)d_in[13];
  const float* W2    = (const float*)d_in[14];
  const float* Wf1   = (const float*)d_in[15];
  const float* bf1   = (const float*)d_in[16];
  const float* Wf2   = (const float*)d_in[17];
  const float* bf2   = (const float*)d_in[18];
  const float* Wf3   = (const float*)d_in[19];
  const float* bf3   = (const float*)d_in[20];
  const float* bn1g  = (const float*)d_in[21];
  const float* bn1b  = (const float*)d_in[22];
  const float* bn2g  = (const float*)d_in[23];
  const float* bn2b  = (const float*)d_in[24];
  float* out = (float*)d_out;
  const int E = in_sizes[1];

  // workspace layout (~90 MB)
  char* w = (char*)d_ws;
  int* deg  = (int*)w; w += alignup((size_t)N_NODES*4);
  int* rp   = (int*)w; w += alignup((size_t)(N_NODES+1)*4);
  int* cur  = (int*)w; w += alignup((size_t)N_NODES*4);
  int* part = (int*)w; w += alignup(512*4);
  int* col  = (int*)w; w += alignup((size_t)E*4);
  float* bufA = (float*)w; w += alignup((size_t)N_NODES*100*4);  // t1, later t2+h2
  float* bufB = (float*)w; w += alignup((size_t)N_NODES*100*4);  // h1
  float* hg  = (float*)w; w += alignup((size_t)B_GRAPH*20*4);
  float* hG  = (float*)w; w += alignup((size_t)B_GRAPH*64*4);
  float* hD  = (float*)w; w += alignup((size_t)B_GRAPH*64*4);
  float* fus = (float*)w; w += alignup((size_t)B_GRAPH*128*4);
  float* y1  = (float*)w; w += alignup((size_t)B_GRAPH*128*4);
  float* y2  = (float*)w; w += alignup((size_t)B_GRAPH*32*4);
  float* t2 = bufA;                   // [N,20]
  float* h2 = bufA + (size_t)N_NODES*20;  // [N,20], disjoint from t2

  hipMemsetAsync(deg, 0, (size_t)N_NODES*sizeof(int), stream);

  int eb = (E + 255)/256;
  k_deg     <<<eb, 256, 0, stream>>>(dst, deg, E);
  k_part    <<<NPART, 256, 0, stream>>>(deg, part, N_NODES);
  k_scanpart<<<1, 512, 0, stream>>>(part, NPART);
  k_rowptr  <<<NPART, 256, 0, stream>>>(deg, part, rp, cur, N_NODES);
  k_fill    <<<eb, 256, 0, stream>>>(src, dst, cur, col, E);

  k_gemm1   <<<(N_NODES+255)/256, 256, 0, stream>>>(feat, Wg1, bufA, N_NODES);
  k_agg1    <<<(N_NODES+1)/2, 256, 0, stream>>>(bufA, rp, col, bg1, bufB, N_NODES);
  k_gemm2   <<<(N_NODES+255)/256, 256, 0, stream>>>(bufB, Wg2, t2, N_NODES);
  k_agg2    <<<(N_NODES+7)/8, 256, 0, stream>>>(t2, rp, col, bg2, h2, N_NODES);

  k_gmean   <<<B_GRAPH, 64, 0, stream>>>(h2, hg);
  k_head1   <<<(B_GRAPH*64)/256, 256, 0, stream>>>(hg, Wpg, bpg, desc2, Wp2, bp2, hG, hD);
  k_head2   <<<(B_GRAPH*64)/256, 256, 0, stream>>>(hG, hD, W2, fus);
  k_bn      <<<128, 256, 0, stream>>>(fus, Wf1, bf1, bn1g, bn1b, y1, 128, 128);
  k_bn      <<<32, 256, 0, stream>>>(y1, Wf2, bf2, bn2g, bn2b, y2, 128, 32);
  k_out     <<<4, 256, 0, stream>>>(y2, Wf3, bf3, out);
}

// Round 2
// 687.237 us; speedup vs baseline: 1.2776x; 1.2776x over previous
//
#include <hip/hip_runtime.h>
#include <math.h>

#define N_NODES 100000
#define B_GRAPH 1024
#define NPART 391   // ceil(N/256)

typedef unsigned short ushort_t;
typedef unsigned int uint_t;

static inline size_t alignup(size_t x){ return (x + 255) & ~(size_t)255; }

__device__ inline float bf2f(ushort_t u){
  union{ uint_t i; float f; } v; v.i = ((uint_t)u) << 16; return v.f;
}
__device__ inline ushort_t f2bf(float f){
  union{ float f; uint_t i; } v; v.f = f;
  uint_t b = v.i;
  b += 0x7fffu + ((b >> 16) & 1u);   // round-to-nearest-even
  return (ushort_t)(b >> 16);
}
__device__ inline uint_t packbf(float a, float b){
  return (uint_t)f2bf(a) | ((uint_t)f2bf(b) << 16);
}

// ---------------- CSR build ----------------
__global__ __launch_bounds__(256) void k_deg(const int* __restrict__ dst, int* __restrict__ deg, int E){
  int e = blockIdx.x*256 + threadIdx.x;
  if (e < E) atomicAdd(&deg[dst[e]], 1);
}

__global__ __launch_bounds__(256) void k_part(const int* __restrict__ deg, int* __restrict__ part, int Nn){
  __shared__ int red[256];
  int t = threadIdx.x; int i = blockIdx.x*256 + t;
  red[t] = (i < Nn) ? deg[i] : 0;
  __syncthreads();
  for (int s = 128; s > 0; s >>= 1){ if (t < s) red[t] += red[t+s]; __syncthreads(); }
  if (t == 0) part[blockIdx.x] = red[0];
}

__global__ __launch_bounds__(512) void k_scanpart(int* __restrict__ part, int np){
  __shared__ int sc[512];
  int t = threadIdx.x;
  int v = (t < np) ? part[t] : 0;
  sc[t] = v; __syncthreads();
  for (int off = 1; off < 512; off <<= 1){
    int u = (t >= off) ? sc[t-off] : 0;
    __syncthreads();
    sc[t] += u;
    __syncthreads();
  }
  if (t < np) part[t] = sc[t] - v;  // exclusive prefix of block sums
}

__global__ __launch_bounds__(256) void k_rowptr(const int* __restrict__ deg, const int* __restrict__ part,
                                                int* __restrict__ rp, int* __restrict__ cur, int Nn){
  __shared__ int sc[256];
  int t = threadIdx.x; int i = blockIdx.x*256 + t;
  int v = (i < Nn) ? deg[i] : 0;
  sc[t] = v; __syncthreads();
  for (int off = 1; off < 256; off <<= 1){
    int u = (t >= off) ? sc[t-off] : 0;
    __syncthreads();
    sc[t] += u;
    __syncthreads();
  }
  int excl = sc[t] - v + part[blockIdx.x];
  if (i < Nn){
    rp[i] = excl; cur[i] = excl;
    if (i == Nn-1) rp[Nn] = excl + v;
  }
}

__global__ __launch_bounds__(256) void k_fill(const int* __restrict__ src, const int* __restrict__ dst,
                                              int* __restrict__ cur, int* __restrict__ col, int E){
  int e = blockIdx.x*256 + threadIdx.x;
  if (e < E){
    int slot = atomicAdd(&cur[dst[e]], 1);
    col[slot] = src[e];
  }
}

// ---------------- GCN layer 1: t1 = feat @ Wg1 (store bf16) ----------------
__global__ __launch_bounds__(256) void k_gemm1(const float* __restrict__ feat, const float* __restrict__ W,
                                               ushort_t* __restrict__ t1, int Nn){
  int row = blockIdx.x*256 + threadIdx.x;
  if (row >= Nn) return;
  const float4* f4 = reinterpret_cast<const float4*>(feat + (size_t)row*128);
  float acc[100];
  #pragma unroll
  for (int j = 0; j < 100; j++) acc[j] = 0.f;
  for (int kc = 0; kc < 32; kc++){
    float4 f = f4[kc];
    const float* w0 = W + kc*400;   // (4*kc)*100
    #pragma unroll
    for (int j = 0; j < 100; j++){
      float a = acc[j];
      a = fmaf(f.x, w0[j],       a);
      a = fmaf(f.y, w0[100 + j], a);
      a = fmaf(f.z, w0[200 + j], a);
      a = fmaf(f.w, w0[300 + j], a);
      acc[j] = a;
    }
  }
  uint2* o = reinterpret_cast<uint2*>(t1 + (size_t)row*100);
  #pragma unroll
  for (int j = 0; j < 25; j++){
    uint2 v; v.x = packbf(acc[4*j], acc[4*j+1]); v.y = packbf(acc[4*j+2], acc[4*j+3]);
    o[j] = v;
  }
}

// ---------------- aggregation, D=100: h1 = relu(mean_in(t1) + bg1) ----------------
__global__ __launch_bounds__(256) void k_agg1(const ushort_t* __restrict__ t1, const int* __restrict__ rp,
                                              const int* __restrict__ col, const float* __restrict__ bias,
                                              float* __restrict__ h1, int Nn){
  int tid = threadIdx.x;
  int node = blockIdx.x*2 + (tid >> 7);
  int d = tid & 127;
  if (node >= Nn || d >= 100) return;
  int rs = rp[node], re = rp[node+1];
  float s = 0.f;
  int e = rs;
  for (; e + 4 <= re; e += 4){
    int c0 = col[e], c1 = col[e+1], c2 = col[e+2], c3 = col[e+3];
    ushort_t u0 = t1[(size_t)c0*100 + d];
    ushort_t u1 = t1[(size_t)c1*100 + d];
    ushort_t u2 = t1[(size_t)c2*100 + d];
    ushort_t u3 = t1[(size_t)c3*100 + d];
    s += bf2f(u0) + bf2f(u1) + bf2f(u2) + bf2f(u3);
  }
  for (; e < re; e++){
    s += bf2f(t1[(size_t)col[e]*100 + d]);
  }
  float v = s / (float)(re - rs) + bias[d];
  h1[(size_t)node*100 + d] = v > 0.f ? v : 0.f;
}

// ---------------- GCN layer 2 GEMM: t2 = h1 @ Wg2 (100->20, store bf16) ----------------
__global__ __launch_bounds__(256) void k_gemm2(const float* __restrict__ h1, const float* __restrict__ W,
                                               ushort_t* __restrict__ t2, int Nn){
  int row = blockIdx.x*256 + threadIdx.x;
  if (row >= Nn) return;
  const float4* f4 = reinterpret_cast<const float4*>(h1 + (size_t)row*100);
  float acc[20];
  #pragma unroll
  for (int j = 0; j < 20; j++) acc[j] = 0.f;
  for (int kc = 0; kc < 25; kc++){
    float4 f = f4[kc];
    const float* w0 = W + kc*80;    // (4*kc)*20
    #pragma unroll
    for (int j = 0; j < 20; j++){
      float a = acc[j];
      a = fmaf(f.x, w0[j],      a);
      a = fmaf(f.y, w0[20 + j], a);
      a = fmaf(f.z, w0[40 + j], a);
      a = fmaf(f.w, w0[60 + j], a);
      acc[j] = a;
    }
  }
  uint2* o = reinterpret_cast<uint2*>(t2 + (size_t)row*20);
  #pragma unroll
  for (int j = 0; j < 5; j++){
    uint2 v; v.x = packbf(acc[4*j], acc[4*j+1]); v.y = packbf(acc[4*j+2], acc[4*j+3]);
    o[j] = v;
  }
}

// ---------------- aggregation, D=20 ----------------
__global__ __launch_bounds__(256) void k_agg2(const ushort_t* __restrict__ t2, const int* __restrict__ rp,
                                              const int* __restrict__ col, const float* __restrict__ bias,
                                              float* __restrict__ h2, int Nn){
  int tid = threadIdx.x;
  int node = blockIdx.x*8 + (tid >> 5);
  int d = tid & 31;
  if (node >= Nn || d >= 20) return;
  int rs = rp[node], re = rp[node+1];
  float s = 0.f;
  int e = rs;
  for (; e + 4 <= re; e += 4){
    int c0 = col[e], c1 = col[e+1], c2 = col[e+2], c3 = col[e+3];
    ushort_t u0 = t2[(size_t)c0*20 + d];
    ushort_t u1 = t2[(size_t)c1*20 + d];
    ushort_t u2 = t2[(size_t)c2*20 + d];
    ushort_t u3 = t2[(size_t)c3*20 + d];
    s += bf2f(u0) + bf2f(u1) + bf2f(u2) + bf2f(u3);
  }
  for (; e < re; e++){
    s += bf2f(t2[(size_t)col[e]*20 + d]);
  }
  float v = s / (float)(re - rs) + bias[d];
  h2[(size_t)node*20 + d] = v > 0.f ? v : 0.f;
}

// ---------------- per-graph mean: hg[g] = mean over nodes of h2 ----------------
// block per graph; 240 active threads: d = t%20, row-group r0 = t/20 (12 groups)
__global__ __launch_bounds__(256) void k_gmean(const float* __restrict__ h2, float* __restrict__ hg){
  __shared__ float red[240];
  int g = blockIdx.x;
  int t = threadIdx.x;
  int s = (int)(((long long)g      * N_NODES + B_GRAPH - 1) / B_GRAPH);
  int e = (int)(((long long)(g+1)  * N_NODES + B_GRAPH - 1) / B_GRAPH);
  if (t < 240){
    int d  = t % 20;
    int r0 = t / 20;
    float acc = 0.f;
    for (int n = s + r0; n < e; n += 12) acc += h2[(size_t)n*20 + d];
    red[t] = acc;
  }
  __syncthreads();
  if (t < 20){
    float acc = 0.f;
    #pragma unroll
    for (int r = 0; r < 12; r++) acc += red[r*20 + t];
    hg[g*20 + t] = acc / (float)(e - s);
  }
}

// ---------------- head: h_g = hg@Wpg+bpg ; h_d = desc2@Wp2+bp2 ----------------
__global__ __launch_bounds__(256) void k_head1(const float* __restrict__ hg, const float* __restrict__ Wpg,
                                               const float* __restrict__ bpg, const float* __restrict__ desc2,
                                               const float* __restrict__ Wp2, const float* __restrict__ bp2,
                                               float* __restrict__ hG, float* __restrict__ hD){
  int idx = blockIdx.x*256 + threadIdx.x;
  if (idx >= B_GRAPH*64) return;
  int r = idx >> 6, d = idx & 63;
  float a = bpg[d];
  for (int k = 0; k < 20; k++) a = fmaf(hg[r*20 + k], Wpg[k*64 + d], a);
  hG[r*64 + d] = a;
  float c = bp2[d];
  for (int k = 0; k < 200; k++) c = fmaf(desc2[r*200 + k], Wp2[k*64 + d], c);
  hD[r*64 + d] = c;
}

// ---------------- head: gate + fusion ----------------
__global__ __launch_bounds__(256) void k_head2(const float* __restrict__ hG, const float* __restrict__ hD,
                                               const float* __restrict__ W2, float* __restrict__ fus){
  int idx = blockIdx.x*256 + threadIdx.x;
  if (idx >= B_GRAPH*64) return;
  int r = idx >> 6, d = idx & 63;
  float x = 0.f;
  for (int k = 0; k < 64; k++) x = fmaf(hG[r*64 + k], W2[k*64 + d], x);
  float hd = hD[r*64 + d];
  float gv = 1.f / (1.f + expf(-x*hd));
  fus[r*128 + d]      = hG[r*64 + d];
  fus[r*128 + 64 + d] = gv*hd;
}

// ---------------- fused linear + BatchNorm(train stats) + relu ----------------
__global__ __launch_bounds__(256) void k_bn(const float* __restrict__ X, const float* __restrict__ W,
                                            const float* __restrict__ bias, const float* __restrict__ gam,
                                            const float* __restrict__ bet, float* __restrict__ Y,
                                            int Kin, int Jout){
  int j = blockIdx.x;
  int t = threadIdx.x;
  float z[4];
  #pragma unroll
  for (int i = 0; i < 4; i++){
    int r = t + i*256;
    const float* xr = X + (size_t)r*Kin;
    float a = bias[j];
    for (int k = 0; k < Kin; k++) a = fmaf(xr[k], W[k*Jout + j], a);
    z[i] = a;
  }
  float s = z[0]+z[1]+z[2]+z[3];
  float q = z[0]*z[0]+z[1]*z[1]+z[2]*z[2]+z[3]*z[3];
  __shared__ float rs_[256], rq_[256];
  rs_[t] = s; rq_[t] = q; __syncthreads();
  for (int o = 128; o > 0; o >>= 1){
    if (t < o){ rs_[t] += rs_[t+o]; rq_[t] += rq_[t+o]; }
    __syncthreads();
  }
  float mu  = rs_[0] * (1.f/1024.f);
  float var = rq_[0] * (1.f/1024.f) - mu*mu;
  float inv = 1.f / sqrtf(var + 1e-5f);
  float gj = gam[j], bj = bet[j];
  #pragma unroll
  for (int i = 0; i < 4; i++){
    int r = t + i*256;
    float v = gj*(z[i]-mu)*inv + bj;
    Y[(size_t)r*Jout + j] = v > 0.f ? v : 0.f;
  }
}

// ---------------- final linear [B,32]@[32,1] ----------------
__global__ __launch_bounds__(256) void k_out(const float* __restrict__ y2, const float* __restrict__ Wf3,
                                             const float* __restrict__ bf3, float* __restrict__ out){
  int r = blockIdx.x*256 + threadIdx.x;
  if (r >= B_GRAPH) return;
  float a = bf3[0];
  #pragma unroll
  for (int k = 0; k < 32; k++) a = fmaf(y2[r*32 + k], Wf3[k], a);
  out[r] = a;
}

extern "C" void kernel_launch(void* const* d_in, const int* in_sizes, int n_in,
                              void* d_out, int out_size, void* d_ws, size_t ws_size,
                              hipStream_t stream){
  const float* feat  = (const float*)d_in[0];
  const int*   src   = (const int*)d_in[1];
  const int*   dst   = (const int*)d_in[2];
  const float* desc2 = (const float*)d_in[4];
  const float* Wg1   = (const float*)d_in[6];
  const float* bg1   = (const float*)d_in[7];
  const float* Wg2   = (const float*)d_in[8];
  const float* bg2   = (const float*)d_in[9];
  const float* Wpg   = (const float*)d_in[10];
  const float* bpg   = (const float*)d_in[11];
  const float* Wp2   = (const float*)d_in[12];
  const float* bp2   = (const float*)d_in[13];
  const float* W2    = (const float*)d_in[14];
  const float* Wf1   = (const float*)d_in[15];
  const float* bf1   = (const float*)d_in[16];
  const float* Wf2   = (const float*)d_in[17];
  const float* bf2   = (const float*)d_in[18];
  const float* Wf3   = (const float*)d_in[19];
  const float* bf3   = (const float*)d_in[20];
  const float* bn1g  = (const float*)d_in[21];
  const float* bn1b  = (const float*)d_in[22];
  const float* bn2g  = (const float*)d_in[23];
  const float* bn2b  = (const float*)d_in[24];
  float* out = (float*)d_out;
  const int E = in_sizes[1];

  // workspace layout (~70 MB)
  char* w = (char*)d_ws;
  int* deg  = (int*)w; w += alignup((size_t)N_NODES*4);
  int* rp   = (int*)w; w += alignup((size_t)(N_NODES+1)*4);
  int* cur  = (int*)w; w += alignup((size_t)N_NODES*4);
  int* part = (int*)w; w += alignup(512*4);
  int* col  = (int*)w; w += alignup((size_t)E*4);
  ushort_t* t1 = (ushort_t*)w; w += alignup((size_t)N_NODES*100*2);   // bf16 [N,100]
  float* h1   = (float*)w; w += alignup((size_t)N_NODES*100*4);       // fp32 [N,100]
  ushort_t* t2 = (ushort_t*)w; w += alignup((size_t)N_NODES*20*2);    // bf16 [N,20]
  float* h2   = (float*)w; w += alignup((size_t)N_NODES*20*4);        // fp32 [N,20]
  float* hg  = (float*)w; w += alignup((size_t)B_GRAPH*20*4);
  float* hG  = (float*)w; w += alignup((size_t)B_GRAPH*64*4);
  float* hD  = (float*)w; w += alignup((size_t)B_GRAPH*64*4);
  float* fus = (float*)w; w += alignup((size_t)B_GRAPH*128*4);
  float* y1  = (float*)w; w += alignup((size_t)B_GRAPH*128*4);
  float* y2  = (float*)w; w += alignup((size_t)B_GRAPH*32*4);

  hipMemsetAsync(deg, 0, (size_t)N_NODES*sizeof(int), stream);

  int eb = (E + 255)/256;
  k_deg     <<<eb, 256, 0, stream>>>(dst, deg, E);
  k_part    <<<NPART, 256, 0, stream>>>(deg, part, N_NODES);
  k_scanpart<<<1, 512, 0, stream>>>(part, NPART);
  k_rowptr  <<<NPART, 256, 0, stream>>>(deg, part, rp, cur, N_NODES);
  k_fill    <<<eb, 256, 0, stream>>>(src, dst, cur, col, E);

  k_gemm1   <<<(N_NODES+255)/256, 256, 0, stream>>>(feat, Wg1, t1, N_NODES);
  k_agg1    <<<(N_NODES+1)/2, 256, 0, stream>>>(t1, rp, col, bg1, h1, N_NODES);
  k_gemm2   <<<(N_NODES+255)/256, 256, 0, stream>>>(h1, Wg2, t2, N_NODES);
  k_agg2    <<<(N_NODES+7)/8, 256, 0, stream>>>(t2, rp, col, bg2, h2, N_NODES);

  k_gmean   <<<B_GRAPH, 256, 0, stream>>>(h2, hg);
  k_head1   <<<(B_GRAPH*64)/256, 256, 0, stream>>>(hg, Wpg, bpg, desc2, Wp2, bp2, hG, hD);
  k_head2   <<<(B_GRAPH*64)/256, 256, 0, stream>>>(hG, hD, W2, fus);
  k_bn      <<<128, 256, 0, stream>>>(fus, Wf1, bf1, bn1g, bn1b, y1, 128, 128);
  k_bn      <<<32, 256, 0, stream>>>(y1, Wf2, bf2, bn2g, bn2b, y2, 128, 32);
  k_out     <<<4, 256, 0, stream>>>(y2, Wf3, bf3, out);
}